// Round 7
// baseline (552.185 us; speedup 1.0000x reference)
//
#include <hip/hip_runtime.h>
#include <math.h>

// Problem constants
#define BQ      16          // batch
#define CDIM    256         // model dim
#define TLEN    1024        // sequence length
#define CTXL    48          // context length
#define CHUNKL  16
#define NLAYER  4
#define NHEADS  8
#define DHEAD   32          // 256/8
#define FFDIM   1024
#define NWIN    64          // T / CHUNK
#define EXTL    1072        // CTX_LEN + T
#define QKV_N   768

typedef __attribute__((ext_vector_type(4))) float floatx4;
typedef __attribute__((ext_vector_type(8))) __bf16 bf16x8;

__device__ __forceinline__ unsigned short f2bf(float f) {
    unsigned int u = __float_as_uint(f);
    u += 0x7fff + ((u >> 16) & 1);          // RNE
    return (unsigned short)(u >> 16);
}
__device__ __forceinline__ float bf2f(unsigned short h) {
    return __uint_as_float(((unsigned int)h) << 16);
}

// ---------------------------------------------------------------------------
// Multi-segment fp32 -> bf16 convert. blockIdx.y picks tensor.
// ---------------------------------------------------------------------------
__global__ void f2b_multi_kernel(const float* __restrict__ p0,
                                 const float* __restrict__ p1,
                                 const float* __restrict__ p2,
                                 const float* __restrict__ p3,
                                 const float* __restrict__ p4,
                                 unsigned short* __restrict__ q0,
                                 unsigned short* __restrict__ q1,
                                 unsigned short* __restrict__ q2,
                                 unsigned short* __restrict__ q3,
                                 unsigned short* __restrict__ q4) {
    const int sizes[5] = {786432, 262144, 1048576, 1048576, 786432};
    const float* ins[5] = {p0, p1, p2, p3, p4};
    unsigned short* outs[5] = {q0, q1, q2, q3, q4};
    int seg = blockIdx.y;
    int i = (blockIdx.x * 256 + threadIdx.x) * 4;
    if (i < sizes[seg]) {
        float4 v = *(const float4*)(ins[seg] + i);
        ushort4 o;
        o.x = f2bf(v.x); o.y = f2bf(v.y); o.z = f2bf(v.z); o.w = f2bf(v.w);
        *(ushort4*)(outs[seg] + i) = o;
    }
}

// ---------------------------------------------------------------------------
// Fused depthwise causal conv + transpose + layer-0 ctx write.
// Grid (T/128, C/32, B), 256 threads. Tile: 32 channels x 128 tokens.
// ---------------------------------------------------------------------------
__global__ __launch_bounds__(256) void conv_t_kernel(
    const float* __restrict__ x, const float* __restrict__ emb,
    unsigned short* __restrict__ actbf, float* __restrict__ ctxo) {
    int t0 = blockIdx.x * 128;
    int c0 = blockIdx.y * 32;
    int b  = blockIdx.z;
    __shared__ float xs[32][164];     // [c][u], u: t0-31 .. t0+128
    __shared__ float filt[32][33];
    int tid = threadIdx.x;

#pragma unroll
    for (int s = 0; s < 20; ++s) {
        int li = tid + s * 256;       // < 5120
        int c = li / 160, u = li - c * 160;
        int gt = t0 + u - 31;
        xs[c][u] = (gt >= 0 && gt < TLEN)
            ? x[((size_t)b * CDIM + c0 + c) * TLEN + gt] : 0.f;
    }
#pragma unroll
    for (int s = 0; s < 4; ++s) {
        int li = tid + s * 256;       // < 1024
        int c = li >> 5, l = li & 31;
        const float* e0 = emb + (((size_t)b * 2 + 0) * CDIM + c0 + c) * 32;
        const float* e1 = emb + (((size_t)b * 2 + 1) * CDIM + c0 + c) * 32;
        filt[c][l] = 0.5f * (e0[l] + e1[l]);
    }
    __syncthreads();

    int c = tid & 31;
    int tb = tid >> 5;                // 0..7 -> tokens tb*16 .. +15
    float f[32];
#pragma unroll
    for (int l = 0; l < 32; ++l) f[l] = filt[c][l];
    float4 xq[12];
#pragma unroll
    for (int s = 0; s < 12; ++s)
        xq[s] = *(const float4*)&xs[c][tb * 16 + 4 * s];
    const float* xv = (const float*)xq;   // 48 floats: u = tb*16 + i

    unsigned short* arow = actbf + ((size_t)b * TLEN + t0 + tb * 16) * CDIM + c0 + c;
#pragma unroll
    for (int t = 0; t < 16; ++t) {
        float acc = 0.f;
#pragma unroll
        for (int l = 0; l < 32; ++l) acc += f[l] * xv[t + l];
        arow[(size_t)t * CDIM] = f2bf(acc);
        int gt = t0 + tb * 16 + t;
        if (gt >= TLEN - CTXL)
            ctxo[(((size_t)b * NLAYER + 0) * CTXL + (gt - (TLEN - CTXL)))
                 * CDIM + c0 + c] = acc;
    }
}

// ---------------------------------------------------------------------------
// Transpose bf16 (B,T,C) -> fp32 (B,C,T)   (final output)
// ---------------------------------------------------------------------------
__global__ void transpose_b2f_kernel(const unsigned short* __restrict__ in,
                                     float* __restrict__ out,
                                     int R, int S) {
    __shared__ float tile[32][33];
    int b = blockIdx.z;
    int s0 = blockIdx.x * 32, r0 = blockIdx.y * 32;
    const unsigned short* inb = in + (size_t)b * R * S;
    float* outb = out + (size_t)b * R * S;
    int tx = threadIdx.x, ty = threadIdx.y;
    for (int i = ty; i < 32; i += 8)
        tile[i][tx] = bf2f(inb[(size_t)(r0 + i) * S + s0 + tx]);
    __syncthreads();
    for (int i = ty; i < 32; i += 8)
        outb[(size_t)(s0 + i) * R + r0 + tx] = tile[tx][i];
}

// ---------------------------------------------------------------------------
// bf16 MFMA GEMM (templated tile): out[m][n] = sum_k Arow(m)[k]*W[n][k]
//   + bias[n] (relu optional). BK=64, 256 threads, bf16 output.
// Staging via global_load_lds 16B, XOR-swizzled chunks:
//   chunk (row,kc) at row*8 + (kc ^ (row&7)).
// mode 1 (ext tokens): row -> ctxb (e<48) or A (e-48).
// ---------------------------------------------------------------------------
template<int BM, int BN, int WM, int WN>
__global__ __launch_bounds__(256) void gemm_bf16_kernel(
    const unsigned short* __restrict__ A,
    const unsigned short* __restrict__ ctxb,
    int mode, int layer,
    const unsigned short* __restrict__ W,
    const float* __restrict__ bias,
    unsigned short* __restrict__ outb,
    int M, int N, int K, int relu) {
    constexpr int IA = BM / 32;
    constexpr int IB = BN / 32;
    constexpr int MT = WM / 16;
    constexpr int NTT = WN / 16;
    constexpr int NWX = BN / WN;
    __shared__ __align__(16) char smem[(BM + BN) * 128];
    char* smemA = smem;
    char* smemB = smem + BM * 128;
    int tid = threadIdx.x;
    int lane = tid & 63;
    int wid = tid >> 6;
    int ln = lane & 15, kq = lane >> 4;
    int wm = (wid / NWX) * WM, wn = (wid % NWX) * WN;
    int m0 = blockIdx.y * BM, n0 = blockIdx.x * BN;

    const unsigned short* arow[IA];
    int akc[IA];
    const unsigned short* brow[IB];
    int bkc[IB];
#pragma unroll
    for (int is = 0; is < IA; ++is) {
        int q = tid + is * 256;
        int m = q >> 3;
        akc[is] = ((q & 7) ^ (m & 7)) * 8;
        int mg = m0 + m;
        if (mode == 0) {
            arow[is] = A + (size_t)mg * K;
        } else {
            int b = mg / EXTL;
            int e = mg - b * EXTL;
            arow[is] = (e < CTXL)
                ? ctxb + (((size_t)b * NLAYER + layer) * CTXL + e) * CDIM
                : A + ((size_t)b * TLEN + (e - CTXL)) * CDIM;
        }
    }
#pragma unroll
    for (int is = 0; is < IB; ++is) {
        int q = tid + is * 256;
        int m = q >> 3;
        bkc[is] = ((q & 7) ^ (m & 7)) * 8;
        brow[is] = W + (size_t)(n0 + m) * K;
    }

    floatx4 acc[MT][NTT];
#pragma unroll
    for (int i = 0; i < MT; ++i)
#pragma unroll
        for (int j = 0; j < NTT; ++j) acc[i][j] = (floatx4){0.f, 0.f, 0.f, 0.f};

    for (int kt = 0; kt < K; kt += 64) {
#pragma unroll
        for (int is = 0; is < IA; ++is) {
            int off = (is * 256 + tid) * 16;
            __builtin_amdgcn_global_load_lds(
                (const __attribute__((address_space(1))) unsigned int*)
                    (const void*)(arow[is] + kt + akc[is]),
                (__attribute__((address_space(3))) unsigned int*)
                    (void*)(smemA + off), 16, 0, 0);
        }
#pragma unroll
        for (int is = 0; is < IB; ++is) {
            int off = (is * 256 + tid) * 16;
            __builtin_amdgcn_global_load_lds(
                (const __attribute__((address_space(1))) unsigned int*)
                    (const void*)(brow[is] + kt + bkc[is]),
                (__attribute__((address_space(3))) unsigned int*)
                    (void*)(smemB + off), 16, 0, 0);
        }
        __syncthreads();
#pragma unroll
        for (int s = 0; s < 2; ++s) {
            bf16x8 af[MT], bfv[NTT];
            int kc = s * 4 + kq;
#pragma unroll
            for (int i = 0; i < MT; ++i) {
                int ml = wm + 16 * i + ln;
                af[i] = *(const bf16x8*)(smemA + (ml * 8 + (kc ^ (ml & 7))) * 16);
            }
#pragma unroll
            for (int j = 0; j < NTT; ++j) {
                int nl = wn + 16 * j + ln;
                bfv[j] = *(const bf16x8*)(smemB + (nl * 8 + (kc ^ (nl & 7))) * 16);
            }
#pragma unroll
            for (int i = 0; i < MT; ++i)
#pragma unroll
                for (int j = 0; j < NTT; ++j)
                    acc[i][j] = __builtin_amdgcn_mfma_f32_16x16x32_bf16(
                        af[i], bfv[j], acc[i][j], 0, 0, 0);
        }
        __syncthreads();
    }

#pragma unroll
    for (int i = 0; i < MT; ++i) {
#pragma unroll
        for (int r = 0; r < 4; ++r) {
            int m = m0 + wm + 16 * i + kq * 4 + r;
#pragma unroll
            for (int j = 0; j < NTT; ++j) {
                int n = n0 + wn + 16 * j + ln;
                float v = acc[i][j][r] + bias[n];
                if (relu) v = fmaxf(v, 0.f);
                outb[(size_t)m * N + n] = f2bf(v);
            }
        }
    }
}

// ---------------------------------------------------------------------------
// Fused GEMM + residual + LayerNorm (N = 256 fixed), used for FF2+LN3.
// BM=32, BN=256 (grid 512 = 2 blocks/CU — keep >=2/CU, see R6 post-mortem).
// If clayer >= 0, rows with (m%1024) >= 976 also write fp32 ctx_out.
// ---------------------------------------------------------------------------
__global__ __launch_bounds__(256) void gemm_ln_kernel(
    const unsigned short* __restrict__ A,
    const unsigned short* __restrict__ W,
    const float* __restrict__ bias,
    const unsigned short* __restrict__ resid,
    const float* __restrict__ g,
    const float* __restrict__ beta,
    unsigned short* __restrict__ outb,
    float* __restrict__ ctxo, int clayer,
    int M, int K) {
    __shared__ __align__(16) unsigned short smA[32 * 64];    // 4 KB swizzled
    __shared__ __align__(16) unsigned short smB[256 * 64];   // 32 KB
    __shared__ float rsum[32][4];
    __shared__ float rsqs[32][4];
    int tid = threadIdx.x;
    int lane = tid & 63;
    int wid = tid >> 6;
    int ln = lane & 15, quad = lane >> 4;
    int wn = wid * 64;
    int m0 = blockIdx.x * 32;

    const unsigned short* arow =
        A + (size_t)(m0 + (tid >> 3)) * K + ((tid & 7) ^ ((tid >> 3) & 7)) * 8;
    const unsigned short* brow[8];
#pragma unroll
    for (int is = 0; is < 8; ++is) {
        int q = tid + is * 256;
        int mm = q >> 3;
        brow[is] = W + (size_t)mm * K + ((q & 7) ^ (mm & 7)) * 8;
    }

    floatx4 acc[2][4];
#pragma unroll
    for (int i = 0; i < 2; ++i)
#pragma unroll
        for (int j = 0; j < 4; ++j) acc[i][j] = (floatx4){0.f, 0.f, 0.f, 0.f};

    for (int kt = 0; kt < K; kt += 64) {
        __builtin_amdgcn_global_load_lds(
            (const __attribute__((address_space(1))) unsigned int*)
                (const void*)(arow + kt),
            (__attribute__((address_space(3))) unsigned int*)
                (void*)((char*)smA + tid * 16), 16, 0, 0);
#pragma unroll
        for (int is = 0; is < 8; ++is) {
            __builtin_amdgcn_global_load_lds(
                (const __attribute__((address_space(1))) unsigned int*)
                    (const void*)(brow[is] + kt),
                (__attribute__((address_space(3))) unsigned int*)
                    (void*)((char*)smB + (is * 256 + tid) * 16), 16, 0, 0);
        }
        __syncthreads();
#pragma unroll
        for (int s = 0; s < 2; ++s) {
            int kc = s * 4 + quad;
            bf16x8 af[2], bfv[4];
#pragma unroll
            for (int i = 0; i < 2; ++i) {
                int ml = 16 * i + ln;
                af[i] = *(const bf16x8*)(smA + (ml * 8 + (kc ^ (ml & 7))) * 8);
            }
#pragma unroll
            for (int j = 0; j < 4; ++j) {
                int nl = wn + 16 * j + ln;
                bfv[j] = *(const bf16x8*)(smB + (nl * 8 + (kc ^ (nl & 7))) * 8);
            }
#pragma unroll
            for (int i = 0; i < 2; ++i)
#pragma unroll
                for (int j = 0; j < 4; ++j)
                    acc[i][j] = __builtin_amdgcn_mfma_f32_16x16x32_bf16(
                        af[i], bfv[j], acc[i][j], 0, 0, 0);
        }
        __syncthreads();
    }

#pragma unroll
    for (int i = 0; i < 2; ++i)
#pragma unroll
        for (int r = 0; r < 4; ++r) {
            int m = m0 + 16 * i + quad * 4 + r;
#pragma unroll
            for (int j = 0; j < 4; ++j) {
                int n = wn + 16 * j + ln;
                acc[i][j][r] += bias[n] + bf2f(resid[(size_t)m * CDIM + n]);
            }
        }

#pragma unroll
    for (int i = 0; i < 2; ++i)
#pragma unroll
        for (int r = 0; r < 4; ++r) {
            float s1 = acc[i][0][r] + acc[i][1][r] + acc[i][2][r] + acc[i][3][r];
            float s2 = acc[i][0][r] * acc[i][0][r] + acc[i][1][r] * acc[i][1][r]
                     + acc[i][2][r] * acc[i][2][r] + acc[i][3][r] * acc[i][3][r];
#pragma unroll
            for (int off = 8; off >= 1; off >>= 1) {
                s1 += __shfl_xor(s1, off, 64);
                s2 += __shfl_xor(s2, off, 64);
            }
            if (ln == 0) {
                int row = 16 * i + quad * 4 + r;
                rsum[row][wid] = s1;
                rsqs[row][wid] = s2;
            }
        }
    __syncthreads();

#pragma unroll
    for (int i = 0; i < 2; ++i)
#pragma unroll
        for (int r = 0; r < 4; ++r) {
            int row = 16 * i + quad * 4 + r;
            float tot = rsum[row][0] + rsum[row][1] + rsum[row][2] + rsum[row][3];
            float tsq = rsqs[row][0] + rsqs[row][1] + rsqs[row][2] + rsqs[row][3];
            float mu = tot * (1.f / 256.f);
            float var = tsq * (1.f / 256.f) - mu * mu;
            float inv = rsqrtf(var + 1e-5f);
            int m = m0 + row;
            int t = m & (TLEN - 1), bb = m >> 10;
            bool wctx = (clayer >= 0) && (t >= TLEN - CTXL);
#pragma unroll
            for (int j = 0; j < 4; ++j) {
                int n = wn + 16 * j + ln;
                float y = (acc[i][j][r] - mu) * inv * g[n] + beta[n];
                outb[(size_t)m * CDIM + n] = f2bf(y);
                if (wctx)
                    ctxo[(((size_t)bb * NLAYER + clayer) * CTXL
                          + (t - (TLEN - CTXL))) * CDIM + n] = y;
            }
        }
}

// ---------------------------------------------------------------------------
// Fused attention + Wo projection + residual + LN1.
// One block (256 thr, 4 waves) per (window, batch); each wave 2 heads.
// ---------------------------------------------------------------------------
__global__ __launch_bounds__(256) void attn_wo_ln_kernel(
    const unsigned short* __restrict__ QKV,
    const unsigned short* __restrict__ act,
    const unsigned short* __restrict__ Wo,
    const float* __restrict__ bo,
    const float* __restrict__ g,
    const float* __restrict__ beta,
    unsigned short* __restrict__ x1out) {
    int n = blockIdx.x, b = blockIdx.y;
    __shared__ __align__(16) unsigned short Vt[256][72];      // V^T [d][key]
    __shared__ __align__(16) unsigned short Pb[4][16][72];    // per-wave P
    __shared__ __align__(16) unsigned short Ol[16][264];      // O rows
    __shared__ float rsum[16][4];
    __shared__ float rsqs[16][4];
    int tid = threadIdx.x;
    int lane = tid & 63, wid = tid >> 6;
    int ln = lane & 15, quad = lane >> 4;
    int key0 = n * CHUNKL;
    const unsigned short* base = QKV + (size_t)b * EXTL * QKV_N;

    // stage V^T: V[key][d] -> Vt[d][key]
    {
        int row = tid >> 2;              // key 0..63
        int c0 = (tid & 3) * 64;         // d block
        const unsigned short* vrow =
            base + (size_t)(key0 + row) * QKV_N + 512 + c0;
#pragma unroll
        for (int s = 0; s < 8; ++s) {
            bf16x8 v = *(const bf16x8*)(vrow + 8 * s);
#pragma unroll
            for (int j = 0; j < 8; ++j)
                Vt[c0 + 8 * s + j][row] = ((const unsigned short*)&v)[j];
        }
    }
    __syncthreads();

    const float scale = 0.17677669529663687f;   // 1/sqrt(32)
#pragma unroll
    for (int hh = 0; hh < 2; ++hh) {
        int h = wid * 2 + hh;
        bf16x8 qf = *(const bf16x8*)(base
            + (size_t)(CTXL + key0 + ln) * QKV_N + h * DHEAD + quad * 8);
        floatx4 sc[4];
#pragma unroll
        for (int j = 0; j < 4; ++j) {
            bf16x8 kf = *(const bf16x8*)(base
                + (size_t)(key0 + j * 16 + ln) * QKV_N + 256
                + h * DHEAD + quad * 8);
            sc[j] = __builtin_amdgcn_mfma_f32_16x16x32_bf16(
                qf, kf, (floatx4){0.f, 0.f, 0.f, 0.f}, 0, 0, 0);
        }
        float p[4][4];
#pragma unroll
        for (int r = 0; r < 4; ++r) {
            float mx = -1e30f;
#pragma unroll
            for (int j = 0; j < 4; ++j) mx = fmaxf(mx, sc[j][r]);
            mx = fmaxf(mx, __shfl_xor(mx, 1, 64));
            mx = fmaxf(mx, __shfl_xor(mx, 2, 64));
            mx = fmaxf(mx, __shfl_xor(mx, 4, 64));
            mx = fmaxf(mx, __shfl_xor(mx, 8, 64));
            float sum = 0.f;
#pragma unroll
            for (int j = 0; j < 4; ++j) {
                float e = __expf((sc[j][r] - mx) * scale);
                p[r][j] = e;
                sum += e;
            }
            sum += __shfl_xor(sum, 1, 64);
            sum += __shfl_xor(sum, 2, 64);
            sum += __shfl_xor(sum, 4, 64);
            sum += __shfl_xor(sum, 8, 64);
            float inv = 1.f / sum;
#pragma unroll
            for (int j = 0; j < 4; ++j) p[r][j] *= inv;
        }
#pragma unroll
        for (int r = 0; r < 4; ++r)
#pragma unroll
            for (int j = 0; j < 4; ++j)
                Pb[wid][quad * 4 + r][j * 16 + ln] = f2bf(p[r][j]);
        bf16x8 pa0 = *(const bf16x8*)&Pb[wid][ln][quad * 8];
        bf16x8 pa1 = *(const bf16x8*)&Pb[wid][ln][32 + quad * 8];
#pragma unroll
        for (int jt = 0; jt < 2; ++jt) {
            bf16x8 v0 = *(const bf16x8*)&Vt[h * DHEAD + jt * 16 + ln][quad * 8];
            bf16x8 v1 = *(const bf16x8*)&Vt[h * DHEAD + jt * 16 + ln][32 + quad * 8];
            floatx4 a = __builtin_amdgcn_mfma_f32_16x16x32_bf16(
                pa0, v0, (floatx4){0.f, 0.f, 0.f, 0.f}, 0, 0, 0);
            a = __builtin_amdgcn_mfma_f32_16x16x32_bf16(pa1, v1, a, 0, 0, 0);
            int colb = wid * 64 + hh * 32 + jt * 16 + ln;
#pragma unroll
            for (int r = 0; r < 4; ++r)
                Ol[quad * 4 + r][colb] = f2bf(a[r]);
        }
    }
    __syncthreads();

    // stage 2: x1pre = O @ Wo^T + bo + resid
    floatx4 o2[4];
#pragma unroll
    for (int j = 0; j < 4; ++j) o2[j] = (floatx4){0.f, 0.f, 0.f, 0.f};
#pragma unroll
    for (int s = 0; s < 8; ++s) {
        bf16x8 af = *(const bf16x8*)&Ol[ln][s * 32 + quad * 8];
#pragma unroll
        for (int j = 0; j < 4; ++j) {
            bf16x8 bv = *(const bf16x8*)(Wo
                + (size_t)(wid * 64 + j * 16 + ln) * CDIM + s * 32 + quad * 8);
            o2[j] = __builtin_amdgcn_mfma_f32_16x16x32_bf16(af, bv, o2[j], 0, 0, 0);
        }
    }

    const unsigned short* residb =
        act + ((size_t)b * TLEN + key0) * CDIM;
#pragma unroll
    for (int r = 0; r < 4; ++r) {
        int row = quad * 4 + r;
#pragma unroll
        for (int j = 0; j < 4; ++j) {
            int col = wid * 64 + j * 16 + ln;
            o2[j][r] += bo[col] + bf2f(residb[(size_t)row * CDIM + col]);
        }
    }

#pragma unroll
    for (int r = 0; r < 4; ++r) {
        float s1 = o2[0][r] + o2[1][r] + o2[2][r] + o2[3][r];
        float s2 = o2[0][r] * o2[0][r] + o2[1][r] * o2[1][r]
                 + o2[2][r] * o2[2][r] + o2[3][r] * o2[3][r];
#pragma unroll
        for (int off = 8; off >= 1; off >>= 1) {
            s1 += __shfl_xor(s1, off, 64);
            s2 += __shfl_xor(s2, off, 64);
        }
        if (ln == 0) {
            rsum[quad * 4 + r][wid] = s1;
            rsqs[quad * 4 + r][wid] = s2;
        }
    }
    __syncthreads();

    unsigned short* xout = x1out + ((size_t)b * TLEN + key0) * CDIM;
#pragma unroll
    for (int r = 0; r < 4; ++r) {
        int row = quad * 4 + r;
        float tot = rsum[row][0] + rsum[row][1] + rsum[row][2] + rsum[row][3];
        float tsq = rsqs[row][0] + rsqs[row][1] + rsqs[row][2] + rsqs[row][3];
        float mu = tot * (1.f / 256.f);
        float var = tsq * (1.f / 256.f) - mu * mu;
        float inv = rsqrtf(var + 1e-5f);
#pragma unroll
        for (int j = 0; j < 4; ++j) {
            int col = wid * 64 + j * 16 + ln;
            float y = (o2[j][r] - mu) * inv * g[col] + beta[col];
            xout[(size_t)row * CDIM + col] = f2bf(y);
        }
    }
}

// ---------------------------------------------------------------------------
extern "C" void kernel_launch(void* const* d_in, const int* in_sizes, int n_in,
                              void* d_out, int out_size, void* d_ws, size_t ws_size,
                              hipStream_t stream) {
    const float* x    = (const float*)d_in[0];
    const float* emb  = (const float*)d_in[1];
    const float* ctx  = (const float*)d_in[2];
    const float* Wqkv = (const float*)d_in[3];
    const float* bqkv = (const float*)d_in[4];
    const float* Wo   = (const float*)d_in[5];
    const float* bo   = (const float*)d_in[6];
    const float* W1   = (const float*)d_in[7];
    const float* b1   = (const float*)d_in[8];
    const float* W2   = (const float*)d_in[9];
    const float* b2   = (const float*)d_in[10];
    const float* ln1g = (const float*)d_in[11];
    const float* ln1b = (const float*)d_in[12];
    const float* ln3g = (const float*)d_in[13];
    const float* ln3b = (const float*)d_in[14];

    float* out = (float*)d_out;                        // (B, C, T)
    float* ctx_out = out + (size_t)BQ * CDIM * TLEN;   // (B, 4, 48, C)

    // Workspace layout (bytes)
    char* w = (char*)d_ws;
    unsigned short* actbf  = (unsigned short*)w; w += 8388608;   // (B,T,C)
    unsigned short* x1bf   = (unsigned short*)w; w += 8388608;
    unsigned short* QKVbf  = (unsigned short*)w; w += 26345472;  // (B,1072,768)
    unsigned short* Hbf    = (unsigned short*)w; w += 33554432;  // (B,T,FF)
    unsigned short* ctxbf  = (unsigned short*)w; w += 1572864;
    unsigned short* Wqkvbf = (unsigned short*)w; w += 1572864;
    unsigned short* Wobf   = (unsigned short*)w; w += 524288;
    unsigned short* W1bf   = (unsigned short*)w; w += 2097152;
    unsigned short* W2bf   = (unsigned short*)w; w += 2097152;

    const int NT = BQ * TLEN;   // 16384

    // all weight/ctx conversions in one multi-segment dispatch
    f2b_multi_kernel<<<dim3(1024, 5), 256, 0, stream>>>(
        Wqkv, Wo, W1, W2, ctx, Wqkvbf, Wobf, W1bf, W2bf, ctxbf);

    // fused conv + transpose -> actbf bf16 + layer-0 ctx fp32
    conv_t_kernel<<<dim3(TLEN / 128, CDIM / 32, BQ), 256, 0, stream>>>(
        x, emb, actbf, ctx_out);

    for (int i = 0; i < NLAYER; ++i) {
        const unsigned short* Wqkvb = Wqkvbf + (size_t)i * 3 * CDIM * CDIM;
        const float* bqi = bqkv + (size_t)i * 3 * CDIM;
        const unsigned short* Wob = Wobf + (size_t)i * CDIM * CDIM;
        const float* boi = bo + (size_t)i * CDIM;
        const unsigned short* W1b = W1bf + (size_t)i * FFDIM * CDIM;
        const float* b1i = b1 + (size_t)i * FFDIM;
        const unsigned short* W2b = W2bf + (size_t)i * CDIM * FFDIM;
        const float* b2i = b2 + (size_t)i * CDIM;

        // QKV = [ctx|act] @ Wqkv^T + bqkv  (M=17152, N=768, K=256)
        gemm_bf16_kernel<128, 256, 64, 128><<<dim3(3, 134), 256, 0, stream>>>(
            actbf, ctxbf, 1, i, Wqkvb, bqi, QKVbf, BQ * EXTL, QKV_N, CDIM, 0);
        // fused attention + Wo + residual + LN1 -> x1bf
        attn_wo_ln_kernel<<<dim3(NWIN, BQ), 256, 0, stream>>>(
            QKVbf, actbf, Wob, boi, ln1g + i * CDIM, ln1b + i * CDIM, x1bf);
        // H = relu(x1@W1^T + b1)
        gemm_bf16_kernel<128, 256, 64, 128><<<dim3(4, 128), 256, 0, stream>>>(
            x1bf, nullptr, 0, i, W1b, b1i, Hbf, NT, FFDIM, CDIM, 1);
        // act = LN3(x1 + H@W2^T + b2) -> actbf; also next layer's ctx
        gemm_ln_kernel<<<NT / 32, 256, 0, stream>>>(
            Hbf, W2b, b2i, x1bf, ln3g + i * CDIM, ln3b + i * CDIM,
            actbf, ctx_out, (i < NLAYER - 1) ? (i + 1) : -1, NT, FFDIM);
    }

    // final output: actbf (B,T,C) -> out (B,C,T) fp32
    transpose_b2f_kernel<<<dim3(CDIM / 32, TLEN / 32, BQ), dim3(32, 8), 0,
                           stream>>>(actbf, out, TLEN, CDIM);
}

// Round 8
// 505.093 us; speedup vs baseline: 1.0932x; 1.0932x over previous
//
#include <hip/hip_runtime.h>
#include <math.h>

// Problem constants
#define BQ      16          // batch
#define CDIM    256         // model dim
#define TLEN    1024        // sequence length
#define CTXL    48          // context length
#define CHUNKL  16
#define NLAYER  4
#define NHEADS  8
#define DHEAD   32          // 256/8
#define FFDIM   1024
#define NWIN    64          // T / CHUNK
#define EXTL    1072        // CTX_LEN + T
#define QKV_N   768

typedef __attribute__((ext_vector_type(4))) float floatx4;
typedef __attribute__((ext_vector_type(8))) __bf16 bf16x8;

__device__ __forceinline__ unsigned short f2bf(float f) {
    unsigned int u = __float_as_uint(f);
    u += 0x7fff + ((u >> 16) & 1);          // RNE
    return (unsigned short)(u >> 16);
}
__device__ __forceinline__ float bf2f(unsigned short h) {
    return __uint_as_float(((unsigned int)h) << 16);
}

// ---------------------------------------------------------------------------
// Multi-segment fp32 -> bf16 convert. blockIdx.y picks tensor.
// ---------------------------------------------------------------------------
__global__ void f2b_multi_kernel(const float* __restrict__ p0,
                                 const float* __restrict__ p1,
                                 const float* __restrict__ p2,
                                 const float* __restrict__ p3,
                                 const float* __restrict__ p4,
                                 unsigned short* __restrict__ q0,
                                 unsigned short* __restrict__ q1,
                                 unsigned short* __restrict__ q2,
                                 unsigned short* __restrict__ q3,
                                 unsigned short* __restrict__ q4) {
    const int sizes[5] = {786432, 262144, 1048576, 1048576, 786432};
    const float* ins[5] = {p0, p1, p2, p3, p4};
    unsigned short* outs[5] = {q0, q1, q2, q3, q4};
    int seg = blockIdx.y;
    int i = (blockIdx.x * 256 + threadIdx.x) * 4;
    if (i < sizes[seg]) {
        float4 v = *(const float4*)(ins[seg] + i);
        ushort4 o;
        o.x = f2bf(v.x); o.y = f2bf(v.y); o.z = f2bf(v.z); o.w = f2bf(v.w);
        *(ushort4*)(outs[seg] + i) = o;
    }
}

// ---------------------------------------------------------------------------
// Fused depthwise causal conv + transpose + layer-0 ctx write.
// Grid (T/128, C/32, B), 256 threads. Tile: 32 channels x 128 tokens.
// ---------------------------------------------------------------------------
__global__ __launch_bounds__(256) void conv_t_kernel(
    const float* __restrict__ x, const float* __restrict__ emb,
    unsigned short* __restrict__ actbf, float* __restrict__ ctxo) {
    int t0 = blockIdx.x * 128;
    int c0 = blockIdx.y * 32;
    int b  = blockIdx.z;
    __shared__ float xs[32][164];     // [c][u], u: t0-31 .. t0+128
    __shared__ float filt[32][33];
    int tid = threadIdx.x;

#pragma unroll
    for (int s = 0; s < 20; ++s) {
        int li = tid + s * 256;       // < 5120
        int c = li / 160, u = li - c * 160;
        int gt = t0 + u - 31;
        xs[c][u] = (gt >= 0 && gt < TLEN)
            ? x[((size_t)b * CDIM + c0 + c) * TLEN + gt] : 0.f;
    }
#pragma unroll
    for (int s = 0; s < 4; ++s) {
        int li = tid + s * 256;       // < 1024
        int c = li >> 5, l = li & 31;
        const float* e0 = emb + (((size_t)b * 2 + 0) * CDIM + c0 + c) * 32;
        const float* e1 = emb + (((size_t)b * 2 + 1) * CDIM + c0 + c) * 32;
        filt[c][l] = 0.5f * (e0[l] + e1[l]);
    }
    __syncthreads();

    int c = tid & 31;
    int tb = tid >> 5;                // 0..7 -> tokens tb*16 .. +15
    float f[32];
#pragma unroll
    for (int l = 0; l < 32; ++l) f[l] = filt[c][l];
    float4 xq[12];
#pragma unroll
    for (int s = 0; s < 12; ++s)
        xq[s] = *(const float4*)&xs[c][tb * 16 + 4 * s];
    const float* xv = (const float*)xq;   // 48 floats: u = tb*16 + i

    unsigned short* arow = actbf + ((size_t)b * TLEN + t0 + tb * 16) * CDIM + c0 + c;
#pragma unroll
    for (int t = 0; t < 16; ++t) {
        float acc = 0.f;
#pragma unroll
        for (int l = 0; l < 32; ++l) acc += f[l] * xv[t + l];
        arow[(size_t)t * CDIM] = f2bf(acc);
        int gt = t0 + tb * 16 + t;
        if (gt >= TLEN - CTXL)
            ctxo[(((size_t)b * NLAYER + 0) * CTXL + (gt - (TLEN - CTXL)))
                 * CDIM + c0 + c] = acc;
    }
}

// ---------------------------------------------------------------------------
// Transpose bf16 (B,T,C) -> fp32 (B,C,T)   (final output)
// ---------------------------------------------------------------------------
__global__ void transpose_b2f_kernel(const unsigned short* __restrict__ in,
                                     float* __restrict__ out,
                                     int R, int S) {
    __shared__ float tile[32][33];
    int b = blockIdx.z;
    int s0 = blockIdx.x * 32, r0 = blockIdx.y * 32;
    const unsigned short* inb = in + (size_t)b * R * S;
    float* outb = out + (size_t)b * R * S;
    int tx = threadIdx.x, ty = threadIdx.y;
    for (int i = ty; i < 32; i += 8)
        tile[i][tx] = bf2f(inb[(size_t)(r0 + i) * S + s0 + tx]);
    __syncthreads();
    for (int i = ty; i < 32; i += 8)
        outb[(size_t)(s0 + i) * R + r0 + tx] = tile[tx][i];
}

// ---------------------------------------------------------------------------
// bf16 MFMA GEMM (templated tile): out[m][n] = sum_k Arow(m)[k]*W[n][k]
//   + bias[n] (relu optional). BK=64, 256 threads, bf16 output.
// 128x128/64x64 is the validated sweet spot (R4/R5; R7's 256-wide regressed:
// VGPR ~240 + grid <2/CU — keep >=2 blocks/CU and VGPR <=~170).
// ---------------------------------------------------------------------------
template<int BM, int BN, int WM, int WN>
__global__ __launch_bounds__(256) void gemm_bf16_kernel(
    const unsigned short* __restrict__ A,
    const unsigned short* __restrict__ ctxb,
    int mode, int layer,
    const unsigned short* __restrict__ W,
    const float* __restrict__ bias,
    unsigned short* __restrict__ outb,
    int M, int N, int K, int relu) {
    constexpr int IA = BM / 32;
    constexpr int IB = BN / 32;
    constexpr int MT = WM / 16;
    constexpr int NTT = WN / 16;
    constexpr int NWX = BN / WN;
    __shared__ __align__(16) char smem[(BM + BN) * 128];
    char* smemA = smem;
    char* smemB = smem + BM * 128;
    int tid = threadIdx.x;
    int lane = tid & 63;
    int wid = tid >> 6;
    int ln = lane & 15, kq = lane >> 4;
    int wm = (wid / NWX) * WM, wn = (wid % NWX) * WN;
    int m0 = blockIdx.y * BM, n0 = blockIdx.x * BN;

    const unsigned short* arow[IA];
    int akc[IA];
    const unsigned short* brow[IB];
    int bkc[IB];
#pragma unroll
    for (int is = 0; is < IA; ++is) {
        int q = tid + is * 256;
        int m = q >> 3;
        akc[is] = ((q & 7) ^ (m & 7)) * 8;
        int mg = m0 + m;
        if (mode == 0) {
            arow[is] = A + (size_t)mg * K;
        } else {
            int b = mg / EXTL;
            int e = mg - b * EXTL;
            arow[is] = (e < CTXL)
                ? ctxb + (((size_t)b * NLAYER + layer) * CTXL + e) * CDIM
                : A + ((size_t)b * TLEN + (e - CTXL)) * CDIM;
        }
    }
#pragma unroll
    for (int is = 0; is < IB; ++is) {
        int q = tid + is * 256;
        int m = q >> 3;
        bkc[is] = ((q & 7) ^ (m & 7)) * 8;
        brow[is] = W + (size_t)(n0 + m) * K;
    }

    floatx4 acc[MT][NTT];
#pragma unroll
    for (int i = 0; i < MT; ++i)
#pragma unroll
        for (int j = 0; j < NTT; ++j) acc[i][j] = (floatx4){0.f, 0.f, 0.f, 0.f};

    for (int kt = 0; kt < K; kt += 64) {
#pragma unroll
        for (int is = 0; is < IA; ++is) {
            int off = (is * 256 + tid) * 16;
            __builtin_amdgcn_global_load_lds(
                (const __attribute__((address_space(1))) unsigned int*)
                    (const void*)(arow[is] + kt + akc[is]),
                (__attribute__((address_space(3))) unsigned int*)
                    (void*)(smemA + off), 16, 0, 0);
        }
#pragma unroll
        for (int is = 0; is < IB; ++is) {
            int off = (is * 256 + tid) * 16;
            __builtin_amdgcn_global_load_lds(
                (const __attribute__((address_space(1))) unsigned int*)
                    (const void*)(brow[is] + kt + bkc[is]),
                (__attribute__((address_space(3))) unsigned int*)
                    (void*)(smemB + off), 16, 0, 0);
        }
        __syncthreads();
#pragma unroll
        for (int s = 0; s < 2; ++s) {
            bf16x8 af[MT], bfv[NTT];
            int kc = s * 4 + kq;
#pragma unroll
            for (int i = 0; i < MT; ++i) {
                int ml = wm + 16 * i + ln;
                af[i] = *(const bf16x8*)(smemA + (ml * 8 + (kc ^ (ml & 7))) * 16);
            }
#pragma unroll
            for (int j = 0; j < NTT; ++j) {
                int nl = wn + 16 * j + ln;
                bfv[j] = *(const bf16x8*)(smemB + (nl * 8 + (kc ^ (nl & 7))) * 16);
            }
#pragma unroll
            for (int i = 0; i < MT; ++i)
#pragma unroll
                for (int j = 0; j < NTT; ++j)
                    acc[i][j] = __builtin_amdgcn_mfma_f32_16x16x32_bf16(
                        af[i], bfv[j], acc[i][j], 0, 0, 0);
        }
        __syncthreads();
    }

#pragma unroll
    for (int i = 0; i < MT; ++i) {
#pragma unroll
        for (int r = 0; r < 4; ++r) {
            int m = m0 + wm + 16 * i + kq * 4 + r;
#pragma unroll
            for (int j = 0; j < NTT; ++j) {
                int n = n0 + wn + 16 * j + ln;
                float v = acc[i][j][r] + bias[n];
                if (relu) v = fmaxf(v, 0.f);
                outb[(size_t)m * N + n] = f2bf(v);
            }
        }
    }
}

// ---------------------------------------------------------------------------
// Fused GEMM + residual + LayerNorm (N = 256 fixed), used for FF2+LN3.
// BM=32, BN=256 (grid 512 = 2 blocks/CU — keep >=2/CU, see R6 post-mortem).
// If clayer >= 0, rows with (m%1024) >= 976 also write fp32 ctx_out.
// ---------------------------------------------------------------------------
__global__ __launch_bounds__(256) void gemm_ln_kernel(
    const unsigned short* __restrict__ A,
    const unsigned short* __restrict__ W,
    const float* __restrict__ bias,
    const unsigned short* __restrict__ resid,
    const float* __restrict__ g,
    const float* __restrict__ beta,
    unsigned short* __restrict__ outb,
    float* __restrict__ ctxo, int clayer,
    int M, int K) {
    __shared__ __align__(16) unsigned short smA[32 * 64];    // 4 KB swizzled
    __shared__ __align__(16) unsigned short smB[256 * 64];   // 32 KB
    __shared__ float rsum[32][4];
    __shared__ float rsqs[32][4];
    int tid = threadIdx.x;
    int lane = tid & 63;
    int wid = tid >> 6;
    int ln = lane & 15, quad = lane >> 4;
    int wn = wid * 64;
    int m0 = blockIdx.x * 32;

    const unsigned short* arow =
        A + (size_t)(m0 + (tid >> 3)) * K + ((tid & 7) ^ ((tid >> 3) & 7)) * 8;
    const unsigned short* brow[8];
#pragma unroll
    for (int is = 0; is < 8; ++is) {
        int q = tid + is * 256;
        int mm = q >> 3;
        brow[is] = W + (size_t)mm * K + ((q & 7) ^ (mm & 7)) * 8;
    }

    floatx4 acc[2][4];
#pragma unroll
    for (int i = 0; i < 2; ++i)
#pragma unroll
        for (int j = 0; j < 4; ++j) acc[i][j] = (floatx4){0.f, 0.f, 0.f, 0.f};

    for (int kt = 0; kt < K; kt += 64) {
        __builtin_amdgcn_global_load_lds(
            (const __attribute__((address_space(1))) unsigned int*)
                (const void*)(arow + kt),
            (__attribute__((address_space(3))) unsigned int*)
                (void*)((char*)smA + tid * 16), 16, 0, 0);
#pragma unroll
        for (int is = 0; is < 8; ++is) {
            __builtin_amdgcn_global_load_lds(
                (const __attribute__((address_space(1))) unsigned int*)
                    (const void*)(brow[is] + kt),
                (__attribute__((address_space(3))) unsigned int*)
                    (void*)((char*)smB + (is * 256 + tid) * 16), 16, 0, 0);
        }
        __syncthreads();
#pragma unroll
        for (int s = 0; s < 2; ++s) {
            int kc = s * 4 + quad;
            bf16x8 af[2], bfv[4];
#pragma unroll
            for (int i = 0; i < 2; ++i) {
                int ml = 16 * i + ln;
                af[i] = *(const bf16x8*)(smA + (ml * 8 + (kc ^ (ml & 7))) * 8);
            }
#pragma unroll
            for (int j = 0; j < 4; ++j) {
                int nl = wn + 16 * j + ln;
                bfv[j] = *(const bf16x8*)(smB + (nl * 8 + (kc ^ (nl & 7))) * 8);
            }
#pragma unroll
            for (int i = 0; i < 2; ++i)
#pragma unroll
                for (int j = 0; j < 4; ++j)
                    acc[i][j] = __builtin_amdgcn_mfma_f32_16x16x32_bf16(
                        af[i], bfv[j], acc[i][j], 0, 0, 0);
        }
        __syncthreads();
    }

#pragma unroll
    for (int i = 0; i < 2; ++i)
#pragma unroll
        for (int r = 0; r < 4; ++r) {
            int m = m0 + 16 * i + quad * 4 + r;
#pragma unroll
            for (int j = 0; j < 4; ++j) {
                int n = wn + 16 * j + ln;
                acc[i][j][r] += bias[n] + bf2f(resid[(size_t)m * CDIM + n]);
            }
        }

#pragma unroll
    for (int i = 0; i < 2; ++i)
#pragma unroll
        for (int r = 0; r < 4; ++r) {
            float s1 = acc[i][0][r] + acc[i][1][r] + acc[i][2][r] + acc[i][3][r];
            float s2 = acc[i][0][r] * acc[i][0][r] + acc[i][1][r] * acc[i][1][r]
                     + acc[i][2][r] * acc[i][2][r] + acc[i][3][r] * acc[i][3][r];
#pragma unroll
            for (int off = 8; off >= 1; off >>= 1) {
                s1 += __shfl_xor(s1, off, 64);
                s2 += __shfl_xor(s2, off, 64);
            }
            if (ln == 0) {
                int row = 16 * i + quad * 4 + r;
                rsum[row][wid] = s1;
                rsqs[row][wid] = s2;
            }
        }
    __syncthreads();

#pragma unroll
    for (int i = 0; i < 2; ++i)
#pragma unroll
        for (int r = 0; r < 4; ++r) {
            int row = 16 * i + quad * 4 + r;
            float tot = rsum[row][0] + rsum[row][1] + rsum[row][2] + rsum[row][3];
            float tsq = rsqs[row][0] + rsqs[row][1] + rsqs[row][2] + rsqs[row][3];
            float mu = tot * (1.f / 256.f);
            float var = tsq * (1.f / 256.f) - mu * mu;
            float inv = rsqrtf(var + 1e-5f);
            int m = m0 + row;
            int t = m & (TLEN - 1), bb = m >> 10;
            bool wctx = (clayer >= 0) && (t >= TLEN - CTXL);
#pragma unroll
            for (int j = 0; j < 4; ++j) {
                int n = wn + 16 * j + ln;
                float y = (acc[i][j][r] - mu) * inv * g[n] + beta[n];
                outb[(size_t)m * CDIM + n] = f2bf(y);
                if (wctx)
                    ctxo[(((size_t)bb * NLAYER + clayer) * CTXL
                          + (t - (TLEN - CTXL))) * CDIM + n] = y;
            }
        }
}

// ---------------------------------------------------------------------------
// Fused attention + Wo projection + residual + LN1.
// One block (256 thr, 4 waves) per (window, batch); each wave 2 heads.
// ---------------------------------------------------------------------------
__global__ __launch_bounds__(256) void attn_wo_ln_kernel(
    const unsigned short* __restrict__ QKV,
    const unsigned short* __restrict__ act,
    const unsigned short* __restrict__ Wo,
    const float* __restrict__ bo,
    const float* __restrict__ g,
    const float* __restrict__ beta,
    unsigned short* __restrict__ x1out) {
    int n = blockIdx.x, b = blockIdx.y;
    __shared__ __align__(16) unsigned short Vt[256][72];      // V^T [d][key]
    __shared__ __align__(16) unsigned short Pb[4][16][72];    // per-wave P
    __shared__ __align__(16) unsigned short Ol[16][264];      // O rows
    __shared__ float rsum[16][4];
    __shared__ float rsqs[16][4];
    int tid = threadIdx.x;
    int lane = tid & 63, wid = tid >> 6;
    int ln = lane & 15, quad = lane >> 4;
    int key0 = n * CHUNKL;
    const unsigned short* base = QKV + (size_t)b * EXTL * QKV_N;

    // stage V^T: V[key][d] -> Vt[d][key]
    {
        int row = tid >> 2;              // key 0..63
        int c0 = (tid & 3) * 64;         // d block
        const unsigned short* vrow =
            base + (size_t)(key0 + row) * QKV_N + 512 + c0;
#pragma unroll
        for (int s = 0; s < 8; ++s) {
            bf16x8 v = *(const bf16x8*)(vrow + 8 * s);
#pragma unroll
            for (int j = 0; j < 8; ++j)
                Vt[c0 + 8 * s + j][row] = ((const unsigned short*)&v)[j];
        }
    }
    __syncthreads();

    const float scale = 0.17677669529663687f;   // 1/sqrt(32)
#pragma unroll
    for (int hh = 0; hh < 2; ++hh) {
        int h = wid * 2 + hh;
        bf16x8 qf = *(const bf16x8*)(base
            + (size_t)(CTXL + key0 + ln) * QKV_N + h * DHEAD + quad * 8);
        floatx4 sc[4];
#pragma unroll
        for (int j = 0; j < 4; ++j) {
            bf16x8 kf = *(const bf16x8*)(base
                + (size_t)(key0 + j * 16 + ln) * QKV_N + 256
                + h * DHEAD + quad * 8);
            sc[j] = __builtin_amdgcn_mfma_f32_16x16x32_bf16(
                qf, kf, (floatx4){0.f, 0.f, 0.f, 0.f}, 0, 0, 0);
        }
        float p[4][4];
#pragma unroll
        for (int r = 0; r < 4; ++r) {
            float mx = -1e30f;
#pragma unroll
            for (int j = 0; j < 4; ++j) mx = fmaxf(mx, sc[j][r]);
            mx = fmaxf(mx, __shfl_xor(mx, 1, 64));
            mx = fmaxf(mx, __shfl_xor(mx, 2, 64));
            mx = fmaxf(mx, __shfl_xor(mx, 4, 64));
            mx = fmaxf(mx, __shfl_xor(mx, 8, 64));
            float sum = 0.f;
#pragma unroll
            for (int j = 0; j < 4; ++j) {
                float e = __expf((sc[j][r] - mx) * scale);
                p[r][j] = e;
                sum += e;
            }
            sum += __shfl_xor(sum, 1, 64);
            sum += __shfl_xor(sum, 2, 64);
            sum += __shfl_xor(sum, 4, 64);
            sum += __shfl_xor(sum, 8, 64);
            float inv = 1.f / sum;
#pragma unroll
            for (int j = 0; j < 4; ++j) p[r][j] *= inv;
        }
#pragma unroll
        for (int r = 0; r < 4; ++r)
#pragma unroll
            for (int j = 0; j < 4; ++j)
                Pb[wid][quad * 4 + r][j * 16 + ln] = f2bf(p[r][j]);
        bf16x8 pa0 = *(const bf16x8*)&Pb[wid][ln][quad * 8];
        bf16x8 pa1 = *(const bf16x8*)&Pb[wid][ln][32 + quad * 8];
#pragma unroll
        for (int jt = 0; jt < 2; ++jt) {
            bf16x8 v0 = *(const bf16x8*)&Vt[h * DHEAD + jt * 16 + ln][quad * 8];
            bf16x8 v1 = *(const bf16x8*)&Vt[h * DHEAD + jt * 16 + ln][32 + quad * 8];
            floatx4 a = __builtin_amdgcn_mfma_f32_16x16x32_bf16(
                pa0, v0, (floatx4){0.f, 0.f, 0.f, 0.f}, 0, 0, 0);
            a = __builtin_amdgcn_mfma_f32_16x16x32_bf16(pa1, v1, a, 0, 0, 0);
            int colb = wid * 64 + hh * 32 + jt * 16 + ln;
#pragma unroll
            for (int r = 0; r < 4; ++r)
                Ol[quad * 4 + r][colb] = f2bf(a[r]);
        }
    }
    __syncthreads();

    // stage 2: x1pre = O @ Wo^T + bo + resid
    floatx4 o2[4];
#pragma unroll
    for (int j = 0; j < 4; ++j) o2[j] = (floatx4){0.f, 0.f, 0.f, 0.f};
#pragma unroll
    for (int s = 0; s < 8; ++s) {
        bf16x8 af = *(const bf16x8*)&Ol[ln][s * 32 + quad * 8];
#pragma unroll
        for (int j = 0; j < 4; ++j) {
            bf16x8 bv = *(const bf16x8*)(Wo
                + (size_t)(wid * 64 + j * 16 + ln) * CDIM + s * 32 + quad * 8);
            o2[j] = __builtin_amdgcn_mfma_f32_16x16x32_bf16(af, bv, o2[j], 0, 0, 0);
        }
    }

    const unsigned short* residb =
        act + ((size_t)b * TLEN + key0) * CDIM;
#pragma unroll
    for (int r = 0; r < 4; ++r) {
        int row = quad * 4 + r;
#pragma unroll
        for (int j = 0; j < 4; ++j) {
            int col = wid * 64 + j * 16 + ln;
            o2[j][r] += bo[col] + bf2f(residb[(size_t)row * CDIM + col]);
        }
    }

#pragma unroll
    for (int r = 0; r < 4; ++r) {
        float s1 = o2[0][r] + o2[1][r] + o2[2][r] + o2[3][r];
        float s2 = o2[0][r] * o2[0][r] + o2[1][r] * o2[1][r]
                 + o2[2][r] * o2[2][r] + o2[3][r] * o2[3][r];
#pragma unroll
        for (int off = 8; off >= 1; off >>= 1) {
            s1 += __shfl_xor(s1, off, 64);
            s2 += __shfl_xor(s2, off, 64);
        }
        if (ln == 0) {
            rsum[quad * 4 + r][wid] = s1;
            rsqs[quad * 4 + r][wid] = s2;
        }
    }
    __syncthreads();

    unsigned short* xout = x1out + ((size_t)b * TLEN + key0) * CDIM;
#pragma unroll
    for (int r = 0; r < 4; ++r) {
        int row = quad * 4 + r;
        float tot = rsum[row][0] + rsum[row][1] + rsum[row][2] + rsum[row][3];
        float tsq = rsqs[row][0] + rsqs[row][1] + rsqs[row][2] + rsqs[row][3];
        float mu = tot * (1.f / 256.f);
        float var = tsq * (1.f / 256.f) - mu * mu;
        float inv = rsqrtf(var + 1e-5f);
#pragma unroll
        for (int j = 0; j < 4; ++j) {
            int col = wid * 64 + j * 16 + ln;
            float y = (o2[j][r] - mu) * inv * g[col] + beta[col];
            xout[(size_t)row * CDIM + col] = f2bf(y);
        }
    }
}

// ---------------------------------------------------------------------------
extern "C" void kernel_launch(void* const* d_in, const int* in_sizes, int n_in,
                              void* d_out, int out_size, void* d_ws, size_t ws_size,
                              hipStream_t stream) {
    const float* x    = (const float*)d_in[0];
    const float* emb  = (const float*)d_in[1];
    const float* ctx  = (const float*)d_in[2];
    const float* Wqkv = (const float*)d_in[3];
    const float* bqkv = (const float*)d_in[4];
    const float* Wo   = (const float*)d_in[5];
    const float* bo   = (const float*)d_in[6];
    const float* W1   = (const float*)d_in[7];
    const float* b1   = (const float*)d_in[8];
    const float* W2   = (const float*)d_in[9];
    const float* b2   = (const float*)d_in[10];
    const float* ln1g = (const float*)d_in[11];
    const float* ln1b = (const float*)d_in[12];
    const float* ln3g = (const float*)d_in[13];
    const float* ln3b = (const float*)d_in[14];

    float* out = (float*)d_out;                        // (B, C, T)
    float* ctx_out = out + (size_t)BQ * CDIM * TLEN;   // (B, 4, 48, C)

    // Workspace layout (bytes)
    char* w = (char*)d_ws;
    unsigned short* actbf  = (unsigned short*)w; w += 8388608;   // (B,T,C)
    unsigned short* x1bf   = (unsigned short*)w; w += 8388608;
    unsigned short* QKVbf  = (unsigned short*)w; w += 26345472;  // (B,1072,768)
    unsigned short* Hbf    = (unsigned short*)w; w += 33554432;  // (B,T,FF)
    unsigned short* ctxbf  = (unsigned short*)w; w += 1572864;
    unsigned short* Wqkvbf = (unsigned short*)w; w += 1572864;
    unsigned short* Wobf   = (unsigned short*)w; w += 524288;
    unsigned short* W1bf   = (unsigned short*)w; w += 2097152;
    unsigned short* W2bf   = (unsigned short*)w; w += 2097152;

    const int NT = BQ * TLEN;   // 16384

    // all weight/ctx conversions in one multi-segment dispatch
    f2b_multi_kernel<<<dim3(1024, 5), 256, 0, stream>>>(
        Wqkv, Wo, W1, W2, ctx, Wqkvbf, Wobf, W1bf, W2bf, ctxbf);

    // fused conv + transpose -> actbf bf16 + layer-0 ctx fp32
    conv_t_kernel<<<dim3(TLEN / 128, CDIM / 32, BQ), 256, 0, stream>>>(
        x, emb, actbf, ctx_out);

    for (int i = 0; i < NLAYER; ++i) {
        const unsigned short* Wqkvb = Wqkvbf + (size_t)i * 3 * CDIM * CDIM;
        const float* bqi = bqkv + (size_t)i * 3 * CDIM;
        const unsigned short* Wob = Wobf + (size_t)i * CDIM * CDIM;
        const float* boi = bo + (size_t)i * CDIM;
        const unsigned short* W1b = W1bf + (size_t)i * FFDIM * CDIM;
        const float* b1i = b1 + (size_t)i * FFDIM;
        const unsigned short* W2b = W2bf + (size_t)i * CDIM * FFDIM;
        const float* b2i = b2 + (size_t)i * CDIM;

        // QKV = [ctx|act] @ Wqkv^T + bqkv  (M=17152, N=768, K=256)
        gemm_bf16_kernel<128, 128, 64, 64><<<dim3(6, 134), 256, 0, stream>>>(
            actbf, ctxbf, 1, i, Wqkvb, bqi, QKVbf, BQ * EXTL, QKV_N, CDIM, 0);
        // fused attention + Wo + residual + LN1 -> x1bf
        attn_wo_ln_kernel<<<dim3(NWIN, BQ), 256, 0, stream>>>(
            QKVbf, actbf, Wob, boi, ln1g + i * CDIM, ln1b + i * CDIM, x1bf);
        // H = relu(x1@W1^T + b1)
        gemm_bf16_kernel<128, 128, 64, 64><<<dim3(8, 128), 256, 0, stream>>>(
            x1bf, nullptr, 0, i, W1b, b1i, Hbf, NT, FFDIM, CDIM, 1);
        // act = LN3(x1 + H@W2^T + b2) -> actbf; also next layer's ctx
        gemm_ln_kernel<<<NT / 32, 256, 0, stream>>>(
            Hbf, W2b, b2i, x1bf, ln3g + i * CDIM, ln3b + i * CDIM,
            actbf, ctx_out, (i < NLAYER - 1) ? (i + 1) : -1, NT, FFDIM);
    }

    // final output: actbf (B,T,C) -> out (B,C,T) fp32
    transpose_b2f_kernel<<<dim3(CDIM / 32, TLEN / 32, BQ), dim3(32, 8), 0,
                           stream>>>(actbf, out, TLEN, CDIM);
}

// Round 9
// 495.278 us; speedup vs baseline: 1.1149x; 1.0198x over previous
//
#include <hip/hip_runtime.h>
#include <math.h>

// Problem constants
#define BQ      16          // batch
#define CDIM    256         // model dim
#define TLEN    1024        // sequence length
#define CTXL    48          // context length
#define CHUNKL  16
#define NLAYER  4
#define NHEADS  8
#define DHEAD   32          // 256/8
#define FFDIM   1024
#define NWIN    64          // T / CHUNK
#define EXTL    1072        // CTX_LEN + T
#define QKV_N   768

typedef __attribute__((ext_vector_type(4))) float floatx4;
typedef __attribute__((ext_vector_type(8))) __bf16 bf16x8;

__device__ __forceinline__ unsigned short f2bf(float f) {
    unsigned int u = __float_as_uint(f);
    u += 0x7fff + ((u >> 16) & 1);          // RNE
    return (unsigned short)(u >> 16);
}
__device__ __forceinline__ float bf2f(unsigned short h) {
    return __uint_as_float(((unsigned int)h) << 16);
}

// ---------------------------------------------------------------------------
// Multi-segment fp32 -> bf16 convert. blockIdx.y picks tensor.
// ---------------------------------------------------------------------------
__global__ void f2b_multi_kernel(const float* __restrict__ p0,
                                 const float* __restrict__ p1,
                                 const float* __restrict__ p2,
                                 const float* __restrict__ p3,
                                 const float* __restrict__ p4,
                                 unsigned short* __restrict__ q0,
                                 unsigned short* __restrict__ q1,
                                 unsigned short* __restrict__ q2,
                                 unsigned short* __restrict__ q3,
                                 unsigned short* __restrict__ q4) {
    const int sizes[5] = {786432, 262144, 1048576, 1048576, 786432};
    const float* ins[5] = {p0, p1, p2, p3, p4};
    unsigned short* outs[5] = {q0, q1, q2, q3, q4};
    int seg = blockIdx.y;
    int i = (blockIdx.x * 256 + threadIdx.x) * 4;
    if (i < sizes[seg]) {
        float4 v = *(const float4*)(ins[seg] + i);
        ushort4 o;
        o.x = f2bf(v.x); o.y = f2bf(v.y); o.z = f2bf(v.z); o.w = f2bf(v.w);
        *(ushort4*)(outs[seg] + i) = o;
    }
}

// ---------------------------------------------------------------------------
// Fused depthwise causal conv + transpose + layer-0 ctx write.
// Grid (T/128, C/32, B), 256 threads. Tile: 32 channels x 128 tokens.
// ---------------------------------------------------------------------------
__global__ __launch_bounds__(256) void conv_t_kernel(
    const float* __restrict__ x, const float* __restrict__ emb,
    unsigned short* __restrict__ actbf, float* __restrict__ ctxo) {
    int t0 = blockIdx.x * 128;
    int c0 = blockIdx.y * 32;
    int b  = blockIdx.z;
    __shared__ float xs[32][164];     // [c][u], u: t0-31 .. t0+128
    __shared__ float filt[32][33];
    int tid = threadIdx.x;

#pragma unroll
    for (int s = 0; s < 20; ++s) {
        int li = tid + s * 256;       // < 5120
        int c = li / 160, u = li - c * 160;
        int gt = t0 + u - 31;
        xs[c][u] = (gt >= 0 && gt < TLEN)
            ? x[((size_t)b * CDIM + c0 + c) * TLEN + gt] : 0.f;
    }
#pragma unroll
    for (int s = 0; s < 4; ++s) {
        int li = tid + s * 256;       // < 1024
        int c = li >> 5, l = li & 31;
        const float* e0 = emb + (((size_t)b * 2 + 0) * CDIM + c0 + c) * 32;
        const float* e1 = emb + (((size_t)b * 2 + 1) * CDIM + c0 + c) * 32;
        filt[c][l] = 0.5f * (e0[l] + e1[l]);
    }
    __syncthreads();

    int c = tid & 31;
    int tb = tid >> 5;                // 0..7 -> tokens tb*16 .. +15
    float f[32];
#pragma unroll
    for (int l = 0; l < 32; ++l) f[l] = filt[c][l];
    float4 xq[12];
#pragma unroll
    for (int s = 0; s < 12; ++s)
        xq[s] = *(const float4*)&xs[c][tb * 16 + 4 * s];
    const float* xv = (const float*)xq;   // 48 floats: u = tb*16 + i

    unsigned short* arow = actbf + ((size_t)b * TLEN + t0 + tb * 16) * CDIM + c0 + c;
#pragma unroll
    for (int t = 0; t < 16; ++t) {
        float acc = 0.f;
#pragma unroll
        for (int l = 0; l < 32; ++l) acc += f[l] * xv[t + l];
        arow[(size_t)t * CDIM] = f2bf(acc);
        int gt = t0 + tb * 16 + t;
        if (gt >= TLEN - CTXL)
            ctxo[(((size_t)b * NLAYER + 0) * CTXL + (gt - (TLEN - CTXL)))
                 * CDIM + c0 + c] = acc;
    }
}

// ---------------------------------------------------------------------------
// Transpose bf16 (B,T,C) -> fp32 (B,C,T)   (final output)
// ---------------------------------------------------------------------------
__global__ void transpose_b2f_kernel(const unsigned short* __restrict__ in,
                                     float* __restrict__ out,
                                     int R, int S) {
    __shared__ float tile[32][33];
    int b = blockIdx.z;
    int s0 = blockIdx.x * 32, r0 = blockIdx.y * 32;
    const unsigned short* inb = in + (size_t)b * R * S;
    float* outb = out + (size_t)b * R * S;
    int tx = threadIdx.x, ty = threadIdx.y;
    for (int i = ty; i < 32; i += 8)
        tile[i][tx] = bf2f(inb[(size_t)(r0 + i) * S + s0 + tx]);
    __syncthreads();
    for (int i = ty; i < 32; i += 8)
        outb[(size_t)(s0 + i) * R + r0 + tx] = tile[tx][i];
}

// ---------------------------------------------------------------------------
// bf16 MFMA GEMM (templated tile): out[m][n] = sum_k Arow(m)[k]*W[n][k]
//   + bias[n] (relu optional). BK=64, 256 threads, bf16 output.
// These thin-K GEMMs are barrier-drain latency-bound: occupancy (blocks/CU)
// is the binding constraint, not staging traffic (R5-R8 evidence).
// 64x64/32x32 maximizes co-residency (~5 blocks/CU vs 3 at 128x128).
// ---------------------------------------------------------------------------
template<int BM, int BN, int WM, int WN>
__global__ __launch_bounds__(256) void gemm_bf16_kernel(
    const unsigned short* __restrict__ A,
    const unsigned short* __restrict__ ctxb,
    int mode, int layer,
    const unsigned short* __restrict__ W,
    const float* __restrict__ bias,
    unsigned short* __restrict__ outb,
    int M, int N, int K, int relu) {
    constexpr int IA = BM / 32;
    constexpr int IB = BN / 32;
    constexpr int MT = WM / 16;
    constexpr int NTT = WN / 16;
    constexpr int NWX = BN / WN;
    __shared__ __align__(16) char smem[(BM + BN) * 128];
    char* smemA = smem;
    char* smemB = smem + BM * 128;
    int tid = threadIdx.x;
    int lane = tid & 63;
    int wid = tid >> 6;
    int ln = lane & 15, kq = lane >> 4;
    int wm = (wid / NWX) * WM, wn = (wid % NWX) * WN;
    int m0 = blockIdx.y * BM, n0 = blockIdx.x * BN;

    const unsigned short* arow[IA];
    int akc[IA];
    const unsigned short* brow[IB];
    int bkc[IB];
#pragma unroll
    for (int is = 0; is < IA; ++is) {
        int q = tid + is * 256;
        int m = q >> 3;
        akc[is] = ((q & 7) ^ (m & 7)) * 8;
        int mg = m0 + m;
        if (mode == 0) {
            arow[is] = A + (size_t)mg * K;
        } else {
            int b = mg / EXTL;
            int e = mg - b * EXTL;
            arow[is] = (e < CTXL)
                ? ctxb + (((size_t)b * NLAYER + layer) * CTXL + e) * CDIM
                : A + ((size_t)b * TLEN + (e - CTXL)) * CDIM;
        }
    }
#pragma unroll
    for (int is = 0; is < IB; ++is) {
        int q = tid + is * 256;
        int m = q >> 3;
        bkc[is] = ((q & 7) ^ (m & 7)) * 8;
        brow[is] = W + (size_t)(n0 + m) * K;
    }

    floatx4 acc[MT][NTT];
#pragma unroll
    for (int i = 0; i < MT; ++i)
#pragma unroll
        for (int j = 0; j < NTT; ++j) acc[i][j] = (floatx4){0.f, 0.f, 0.f, 0.f};

    for (int kt = 0; kt < K; kt += 64) {
#pragma unroll
        for (int is = 0; is < IA; ++is) {
            int off = (is * 256 + tid) * 16;
            __builtin_amdgcn_global_load_lds(
                (const __attribute__((address_space(1))) unsigned int*)
                    (const void*)(arow[is] + kt + akc[is]),
                (__attribute__((address_space(3))) unsigned int*)
                    (void*)(smemA + off), 16, 0, 0);
        }
#pragma unroll
        for (int is = 0; is < IB; ++is) {
            int off = (is * 256 + tid) * 16;
            __builtin_amdgcn_global_load_lds(
                (const __attribute__((address_space(1))) unsigned int*)
                    (const void*)(brow[is] + kt + bkc[is]),
                (__attribute__((address_space(3))) unsigned int*)
                    (void*)(smemB + off), 16, 0, 0);
        }
        __syncthreads();
#pragma unroll
        for (int s = 0; s < 2; ++s) {
            bf16x8 af[MT], bfv[NTT];
            int kc = s * 4 + kq;
#pragma unroll
            for (int i = 0; i < MT; ++i) {
                int ml = wm + 16 * i + ln;
                af[i] = *(const bf16x8*)(smemA + (ml * 8 + (kc ^ (ml & 7))) * 16);
            }
#pragma unroll
            for (int j = 0; j < NTT; ++j) {
                int nl = wn + 16 * j + ln;
                bfv[j] = *(const bf16x8*)(smemB + (nl * 8 + (kc ^ (nl & 7))) * 16);
            }
#pragma unroll
            for (int i = 0; i < MT; ++i)
#pragma unroll
                for (int j = 0; j < NTT; ++j)
                    acc[i][j] = __builtin_amdgcn_mfma_f32_16x16x32_bf16(
                        af[i], bfv[j], acc[i][j], 0, 0, 0);
        }
        __syncthreads();
    }

#pragma unroll
    for (int i = 0; i < MT; ++i) {
#pragma unroll
        for (int r = 0; r < 4; ++r) {
            int m = m0 + wm + 16 * i + kq * 4 + r;
#pragma unroll
            for (int j = 0; j < NTT; ++j) {
                int n = n0 + wn + 16 * j + ln;
                float v = acc[i][j][r] + bias[n];
                if (relu) v = fmaxf(v, 0.f);
                outb[(size_t)m * N + n] = f2bf(v);
            }
        }
    }
}

// ---------------------------------------------------------------------------
// Fused GEMM + residual + LayerNorm (N = 256 fixed), used for FF2+LN3.
// BM=32, BN=256 (grid 512 = 2 blocks/CU — keep >=2/CU, see R6 post-mortem).
// If clayer >= 0, rows with (m%1024) >= 976 also write fp32 ctx_out.
// ---------------------------------------------------------------------------
__global__ __launch_bounds__(256) void gemm_ln_kernel(
    const unsigned short* __restrict__ A,
    const unsigned short* __restrict__ W,
    const float* __restrict__ bias,
    const unsigned short* __restrict__ resid,
    const float* __restrict__ g,
    const float* __restrict__ beta,
    unsigned short* __restrict__ outb,
    float* __restrict__ ctxo, int clayer,
    int M, int K) {
    __shared__ __align__(16) unsigned short smA[32 * 64];    // 4 KB swizzled
    __shared__ __align__(16) unsigned short smB[256 * 64];   // 32 KB
    __shared__ float rsum[32][4];
    __shared__ float rsqs[32][4];
    int tid = threadIdx.x;
    int lane = tid & 63;
    int wid = tid >> 6;
    int ln = lane & 15, quad = lane >> 4;
    int wn = wid * 64;
    int m0 = blockIdx.x * 32;

    const unsigned short* arow =
        A + (size_t)(m0 + (tid >> 3)) * K + ((tid & 7) ^ ((tid >> 3) & 7)) * 8;
    const unsigned short* brow[8];
#pragma unroll
    for (int is = 0; is < 8; ++is) {
        int q = tid + is * 256;
        int mm = q >> 3;
        brow[is] = W + (size_t)mm * K + ((q & 7) ^ (mm & 7)) * 8;
    }

    floatx4 acc[2][4];
#pragma unroll
    for (int i = 0; i < 2; ++i)
#pragma unroll
        for (int j = 0; j < 4; ++j) acc[i][j] = (floatx4){0.f, 0.f, 0.f, 0.f};

    for (int kt = 0; kt < K; kt += 64) {
        __builtin_amdgcn_global_load_lds(
            (const __attribute__((address_space(1))) unsigned int*)
                (const void*)(arow + kt),
            (__attribute__((address_space(3))) unsigned int*)
                (void*)((char*)smA + tid * 16), 16, 0, 0);
#pragma unroll
        for (int is = 0; is < 8; ++is) {
            __builtin_amdgcn_global_load_lds(
                (const __attribute__((address_space(1))) unsigned int*)
                    (const void*)(brow[is] + kt),
                (__attribute__((address_space(3))) unsigned int*)
                    (void*)((char*)smB + (is * 256 + tid) * 16), 16, 0, 0);
        }
        __syncthreads();
#pragma unroll
        for (int s = 0; s < 2; ++s) {
            int kc = s * 4 + quad;
            bf16x8 af[2], bfv[4];
#pragma unroll
            for (int i = 0; i < 2; ++i) {
                int ml = 16 * i + ln;
                af[i] = *(const bf16x8*)(smA + (ml * 8 + (kc ^ (ml & 7))) * 8);
            }
#pragma unroll
            for (int j = 0; j < 4; ++j) {
                int nl = wn + 16 * j + ln;
                bfv[j] = *(const bf16x8*)(smB + (nl * 8 + (kc ^ (nl & 7))) * 8);
            }
#pragma unroll
            for (int i = 0; i < 2; ++i)
#pragma unroll
                for (int j = 0; j < 4; ++j)
                    acc[i][j] = __builtin_amdgcn_mfma_f32_16x16x32_bf16(
                        af[i], bfv[j], acc[i][j], 0, 0, 0);
        }
        __syncthreads();
    }

#pragma unroll
    for (int i = 0; i < 2; ++i)
#pragma unroll
        for (int r = 0; r < 4; ++r) {
            int m = m0 + 16 * i + quad * 4 + r;
#pragma unroll
            for (int j = 0; j < 4; ++j) {
                int n = wn + 16 * j + ln;
                acc[i][j][r] += bias[n] + bf2f(resid[(size_t)m * CDIM + n]);
            }
        }

#pragma unroll
    for (int i = 0; i < 2; ++i)
#pragma unroll
        for (int r = 0; r < 4; ++r) {
            float s1 = acc[i][0][r] + acc[i][1][r] + acc[i][2][r] + acc[i][3][r];
            float s2 = acc[i][0][r] * acc[i][0][r] + acc[i][1][r] * acc[i][1][r]
                     + acc[i][2][r] * acc[i][2][r] + acc[i][3][r] * acc[i][3][r];
#pragma unroll
            for (int off = 8; off >= 1; off >>= 1) {
                s1 += __shfl_xor(s1, off, 64);
                s2 += __shfl_xor(s2, off, 64);
            }
            if (ln == 0) {
                int row = 16 * i + quad * 4 + r;
                rsum[row][wid] = s1;
                rsqs[row][wid] = s2;
            }
        }
    __syncthreads();

#pragma unroll
    for (int i = 0; i < 2; ++i)
#pragma unroll
        for (int r = 0; r < 4; ++r) {
            int row = 16 * i + quad * 4 + r;
            float tot = rsum[row][0] + rsum[row][1] + rsum[row][2] + rsum[row][3];
            float tsq = rsqs[row][0] + rsqs[row][1] + rsqs[row][2] + rsqs[row][3];
            float mu = tot * (1.f / 256.f);
            float var = tsq * (1.f / 256.f) - mu * mu;
            float inv = rsqrtf(var + 1e-5f);
            int m = m0 + row;
            int t = m & (TLEN - 1), bb = m >> 10;
            bool wctx = (clayer >= 0) && (t >= TLEN - CTXL);
#pragma unroll
            for (int j = 0; j < 4; ++j) {
                int n = wn + 16 * j + ln;
                float y = (acc[i][j][r] - mu) * inv * g[n] + beta[n];
                outb[(size_t)m * CDIM + n] = f2bf(y);
                if (wctx)
                    ctxo[(((size_t)bb * NLAYER + clayer) * CTXL
                          + (t - (TLEN - CTXL))) * CDIM + n] = y;
            }
        }
}

// ---------------------------------------------------------------------------
// Fused attention + Wo projection + residual + LN1.
// One block (256 thr, 4 waves) per (window, batch); each wave 2 heads.
// ---------------------------------------------------------------------------
__global__ __launch_bounds__(256) void attn_wo_ln_kernel(
    const unsigned short* __restrict__ QKV,
    const unsigned short* __restrict__ act,
    const unsigned short* __restrict__ Wo,
    const float* __restrict__ bo,
    const float* __restrict__ g,
    const float* __restrict__ beta,
    unsigned short* __restrict__ x1out) {
    int n = blockIdx.x, b = blockIdx.y;
    __shared__ __align__(16) unsigned short Vt[256][72];      // V^T [d][key]
    __shared__ __align__(16) unsigned short Pb[4][16][72];    // per-wave P
    __shared__ __align__(16) unsigned short Ol[16][264];      // O rows
    __shared__ float rsum[16][4];
    __shared__ float rsqs[16][4];
    int tid = threadIdx.x;
    int lane = tid & 63, wid = tid >> 6;
    int ln = lane & 15, quad = lane >> 4;
    int key0 = n * CHUNKL;
    const unsigned short* base = QKV + (size_t)b * EXTL * QKV_N;

    // stage V^T: V[key][d] -> Vt[d][key]
    {
        int row = tid >> 2;              // key 0..63
        int c0 = (tid & 3) * 64;         // d block
        const unsigned short* vrow =
            base + (size_t)(key0 + row) * QKV_N + 512 + c0;
#pragma unroll
        for (int s = 0; s < 8; ++s) {
            bf16x8 v = *(const bf16x8*)(vrow + 8 * s);
#pragma unroll
            for (int j = 0; j < 8; ++j)
                Vt[c0 + 8 * s + j][row] = ((const unsigned short*)&v)[j];
        }
    }
    __syncthreads();

    const float scale = 0.17677669529663687f;   // 1/sqrt(32)
#pragma unroll
    for (int hh = 0; hh < 2; ++hh) {
        int h = wid * 2 + hh;
        bf16x8 qf = *(const bf16x8*)(base
            + (size_t)(CTXL + key0 + ln) * QKV_N + h * DHEAD + quad * 8);
        floatx4 sc[4];
#pragma unroll
        for (int j = 0; j < 4; ++j) {
            bf16x8 kf = *(const bf16x8*)(base
                + (size_t)(key0 + j * 16 + ln) * QKV_N + 256
                + h * DHEAD + quad * 8);
            sc[j] = __builtin_amdgcn_mfma_f32_16x16x32_bf16(
                qf, kf, (floatx4){0.f, 0.f, 0.f, 0.f}, 0, 0, 0);
        }
        float p[4][4];
#pragma unroll
        for (int r = 0; r < 4; ++r) {
            float mx = -1e30f;
#pragma unroll
            for (int j = 0; j < 4; ++j) mx = fmaxf(mx, sc[j][r]);
            mx = fmaxf(mx, __shfl_xor(mx, 1, 64));
            mx = fmaxf(mx, __shfl_xor(mx, 2, 64));
            mx = fmaxf(mx, __shfl_xor(mx, 4, 64));
            mx = fmaxf(mx, __shfl_xor(mx, 8, 64));
            float sum = 0.f;
#pragma unroll
            for (int j = 0; j < 4; ++j) {
                float e = __expf((sc[j][r] - mx) * scale);
                p[r][j] = e;
                sum += e;
            }
            sum += __shfl_xor(sum, 1, 64);
            sum += __shfl_xor(sum, 2, 64);
            sum += __shfl_xor(sum, 4, 64);
            sum += __shfl_xor(sum, 8, 64);
            float inv = 1.f / sum;
#pragma unroll
            for (int j = 0; j < 4; ++j) p[r][j] *= inv;
        }
#pragma unroll
        for (int r = 0; r < 4; ++r)
#pragma unroll
            for (int j = 0; j < 4; ++j)
                Pb[wid][quad * 4 + r][j * 16 + ln] = f2bf(p[r][j]);
        bf16x8 pa0 = *(const bf16x8*)&Pb[wid][ln][quad * 8];
        bf16x8 pa1 = *(const bf16x8*)&Pb[wid][ln][32 + quad * 8];
#pragma unroll
        for (int jt = 0; jt < 2; ++jt) {
            bf16x8 v0 = *(const bf16x8*)&Vt[h * DHEAD + jt * 16 + ln][quad * 8];
            bf16x8 v1 = *(const bf16x8*)&Vt[h * DHEAD + jt * 16 + ln][32 + quad * 8];
            floatx4 a = __builtin_amdgcn_mfma_f32_16x16x32_bf16(
                pa0, v0, (floatx4){0.f, 0.f, 0.f, 0.f}, 0, 0, 0);
            a = __builtin_amdgcn_mfma_f32_16x16x32_bf16(pa1, v1, a, 0, 0, 0);
            int colb = wid * 64 + hh * 32 + jt * 16 + ln;
#pragma unroll
            for (int r = 0; r < 4; ++r)
                Ol[quad * 4 + r][colb] = f2bf(a[r]);
        }
    }
    __syncthreads();

    // stage 2: x1pre = O @ Wo^T + bo + resid
    floatx4 o2[4];
#pragma unroll
    for (int j = 0; j < 4; ++j) o2[j] = (floatx4){0.f, 0.f, 0.f, 0.f};
#pragma unroll
    for (int s = 0; s < 8; ++s) {
        bf16x8 af = *(const bf16x8*)&Ol[ln][s * 32 + quad * 8];
#pragma unroll
        for (int j = 0; j < 4; ++j) {
            bf16x8 bv = *(const bf16x8*)(Wo
                + (size_t)(wid * 64 + j * 16 + ln) * CDIM + s * 32 + quad * 8);
            o2[j] = __builtin_amdgcn_mfma_f32_16x16x32_bf16(af, bv, o2[j], 0, 0, 0);
        }
    }

    const unsigned short* residb =
        act + ((size_t)b * TLEN + key0) * CDIM;
#pragma unroll
    for (int r = 0; r < 4; ++r) {
        int row = quad * 4 + r;
#pragma unroll
        for (int j = 0; j < 4; ++j) {
            int col = wid * 64 + j * 16 + ln;
            o2[j][r] += bo[col] + bf2f(residb[(size_t)row * CDIM + col]);
        }
    }

#pragma unroll
    for (int r = 0; r < 4; ++r) {
        float s1 = o2[0][r] + o2[1][r] + o2[2][r] + o2[3][r];
        float s2 = o2[0][r] * o2[0][r] + o2[1][r] * o2[1][r]
                 + o2[2][r] * o2[2][r] + o2[3][r] * o2[3][r];
#pragma unroll
        for (int off = 8; off >= 1; off >>= 1) {
            s1 += __shfl_xor(s1, off, 64);
            s2 += __shfl_xor(s2, off, 64);
        }
        if (ln == 0) {
            rsum[quad * 4 + r][wid] = s1;
            rsqs[quad * 4 + r][wid] = s2;
        }
    }
    __syncthreads();

    unsigned short* xout = x1out + ((size_t)b * TLEN + key0) * CDIM;
#pragma unroll
    for (int r = 0; r < 4; ++r) {
        int row = quad * 4 + r;
        float tot = rsum[row][0] + rsum[row][1] + rsum[row][2] + rsum[row][3];
        float tsq = rsqs[row][0] + rsqs[row][1] + rsqs[row][2] + rsqs[row][3];
        float mu = tot * (1.f / 256.f);
        float var = tsq * (1.f / 256.f) - mu * mu;
        float inv = rsqrtf(var + 1e-5f);
#pragma unroll
        for (int j = 0; j < 4; ++j) {
            int col = wid * 64 + j * 16 + ln;
            float y = (o2[j][r] - mu) * inv * g[col] + beta[col];
            xout[(size_t)row * CDIM + col] = f2bf(y);
        }
    }
}

// ---------------------------------------------------------------------------
extern "C" void kernel_launch(void* const* d_in, const int* in_sizes, int n_in,
                              void* d_out, int out_size, void* d_ws, size_t ws_size,
                              hipStream_t stream) {
    const float* x    = (const float*)d_in[0];
    const float* emb  = (const float*)d_in[1];
    const float* ctx  = (const float*)d_in[2];
    const float* Wqkv = (const float*)d_in[3];
    const float* bqkv = (const float*)d_in[4];
    const float* Wo   = (const float*)d_in[5];
    const float* bo   = (const float*)d_in[6];
    const float* W1   = (const float*)d_in[7];
    const float* b1   = (const float*)d_in[8];
    const float* W2   = (const float*)d_in[9];
    const float* b2   = (const float*)d_in[10];
    const float* ln1g = (const float*)d_in[11];
    const float* ln1b = (const float*)d_in[12];
    const float* ln3g = (const float*)d_in[13];
    const float* ln3b = (const float*)d_in[14];

    float* out = (float*)d_out;                        // (B, C, T)
    float* ctx_out = out + (size_t)BQ * CDIM * TLEN;   // (B, 4, 48, C)

    // Workspace layout (bytes)
    char* w = (char*)d_ws;
    unsigned short* actbf  = (unsigned short*)w; w += 8388608;   // (B,T,C)
    unsigned short* x1bf   = (unsigned short*)w; w += 8388608;
    unsigned short* QKVbf  = (unsigned short*)w; w += 26345472;  // (B,1072,768)
    unsigned short* Hbf    = (unsigned short*)w; w += 33554432;  // (B,T,FF)
    unsigned short* ctxbf  = (unsigned short*)w; w += 1572864;
    unsigned short* Wqkvbf = (unsigned short*)w; w += 1572864;
    unsigned short* Wobf   = (unsigned short*)w; w += 524288;
    unsigned short* W1bf   = (unsigned short*)w; w += 2097152;
    unsigned short* W2bf   = (unsigned short*)w; w += 2097152;

    const int NT = BQ * TLEN;   // 16384

    // all weight/ctx conversions in one multi-segment dispatch
    f2b_multi_kernel<<<dim3(1024, 5), 256, 0, stream>>>(
        Wqkv, Wo, W1, W2, ctx, Wqkvbf, Wobf, W1bf, W2bf, ctxbf);

    // fused conv + transpose -> actbf bf16 + layer-0 ctx fp32
    conv_t_kernel<<<dim3(TLEN / 128, CDIM / 32, BQ), 256, 0, stream>>>(
        x, emb, actbf, ctx_out);

    for (int i = 0; i < NLAYER; ++i) {
        const unsigned short* Wqkvb = Wqkvbf + (size_t)i * 3 * CDIM * CDIM;
        const float* bqi = bqkv + (size_t)i * 3 * CDIM;
        const unsigned short* Wob = Wobf + (size_t)i * CDIM * CDIM;
        const float* boi = bo + (size_t)i * CDIM;
        const unsigned short* W1b = W1bf + (size_t)i * FFDIM * CDIM;
        const float* b1i = b1 + (size_t)i * FFDIM;
        const unsigned short* W2b = W2bf + (size_t)i * CDIM * FFDIM;
        const float* b2i = b2 + (size_t)i * CDIM;

        // QKV = [ctx|act] @ Wqkv^T + bqkv  (M=17152, N=768, K=256)
        // 64x64 tiles: 3216 blocks (~12.6/CU queue, ~5 resident) to hide
        // the per-iteration vmcnt(0) barrier drains.
        gemm_bf16_kernel<64, 64, 32, 32><<<dim3(12, 268), 256, 0, stream>>>(
            actbf, ctxbf, 1, i, Wqkvb, bqi, QKVbf, BQ * EXTL, QKV_N, CDIM, 0);
        // fused attention + Wo + residual + LN1 -> x1bf
        attn_wo_ln_kernel<<<dim3(NWIN, BQ), 256, 0, stream>>>(
            QKVbf, actbf, Wob, boi, ln1g + i * CDIM, ln1b + i * CDIM, x1bf);
        // H = relu(x1@W1^T + b1)
        gemm_bf16_kernel<64, 64, 32, 32><<<dim3(16, 256), 256, 0, stream>>>(
            x1bf, nullptr, 0, i, W1b, b1i, Hbf, NT, FFDIM, CDIM, 1);
        // act = LN3(x1 + H@W2^T + b2) -> actbf; also next layer's ctx
        gemm_ln_kernel<<<NT / 32, 256, 0, stream>>>(
            Hbf, W2b, b2i, x1bf, ln3g + i * CDIM, ln3b + i * CDIM,
            actbf, ctx_out, (i < NLAYER - 1) ? (i + 1) : -1, NT, FFDIM);
    }

    // final output: actbf (B,T,C) -> out (B,C,T) fp32
    transpose_b2f_kernel<<<dim3(CDIM / 32, TLEN / 32, BQ), dim3(32, 8), 0,
                           stream>>>(actbf, out, TLEN, CDIM);
}